// Round 11
// baseline (176.119 us; speedup 1.0000x reference)
//
#include <hip/hip_runtime.h>
#include <hip/hip_fp16.h>

#define HEADS 4
#define F 128
#define NEG_SLOPE 0.2f

#define NB 256        // buckets
#define NPB 196       // nodes/bucket: NB*NPB = 50176 >= N
#define BE 8192       // edges per hist/bscatter block
#define CAPS 6144     // max (edges + self-loops) per bucket

#define LDP 136       // padded LDS row stride in halfs

typedef _Float16 f16x8 __attribute__((ext_vector_type(8)));
typedef _Float16 f16x4 __attribute__((ext_vector_type(4)));
typedef float f32x4 __attribute__((ext_vector_type(4)));

__device__ __forceinline__ float lrelu(float v) { return v > 0.f ? v : NEG_SLOPE * v; }

// ---- merged: blocks 0..gB-1 per-block histogram (plain stores, no zeroing
//      needed); blocks gB..gB+1 convert W -> Wt fp16 [n][k] ----
__global__ __launch_bounds__(256) void k_wcvt_hist(const float* __restrict__ W1,
                                                   const float* __restrict__ W2,
                                                   _Float16* __restrict__ Wt1,
                                                   _Float16* __restrict__ Wt2,
                                                   const int* __restrict__ dst,
                                                   int* __restrict__ histSlots,
                                                   int E, int gB) {
    __shared__ _Float16 l[128][LDP];
    __shared__ int hh[NB];
    int t = threadIdx.x;
    int bx = blockIdx.x;
    if (bx >= gB) {                      // weight convert+transpose
        const float* W = (bx - gB) ? W2 : W1;
        _Float16* Wt = (bx - gB) ? Wt2 : Wt1;
        for (int i = t; i < 4096; i += 256) {
            int k = i >> 5, n4 = (i & 31) << 2;
            float4 v = ((const float4*)W)[i];
            l[n4][k]     = (_Float16)v.x;
            l[n4 + 1][k] = (_Float16)v.y;
            l[n4 + 2][k] = (_Float16)v.z;
            l[n4 + 3][k] = (_Float16)v.w;
        }
        __syncthreads();
        for (int i = t; i < 2048; i += 256) {
            int n = i >> 4, c8 = (i & 15) << 3;
            *(f16x8*)(Wt + n * 128 + c8) = *(const f16x8*)(&l[n][c8]);
        }
        return;
    }
    hh[t] = 0;
    __syncthreads();
    int base = bx * BE;
    int end = min(base + BE, E);
    for (int i = base + t; i < end; i += 256) atomicAdd(&hh[dst[i] / NPB], 1);
    __syncthreads();
    histSlots[bx * NB + t] = hh[t];      // every slot written every call
}

// ---- MFMA GEMM + fused logits: h^T = Wt * X^T ; Hh fp16 ; As/Ad from fp32 acc ----
template <bool FP32IN>
__global__ __launch_bounds__(256) void k_gemm_mfma(const void* __restrict__ Xv,
                                                   const _Float16* __restrict__ Wt,
                                                   const float* __restrict__ asrc,
                                                   const float* __restrict__ adst,
                                                   _Float16* __restrict__ Hh,
                                                   float* __restrict__ As,
                                                   float* __restrict__ Ad, int N) {
    __shared__ _Float16 xs[64 * LDP];
    __shared__ _Float16 ws[128 * LDP];
    int t = threadIdx.x;
    int row0 = blockIdx.x * 64;

    for (int i = t; i < 128 * 16; i += 256) {
        int rw = i >> 4, c8 = (i & 15) << 3;
        *(f16x8*)(ws + rw * LDP + c8) = *(const f16x8*)(Wt + rw * 128 + c8);
    }
    if (FP32IN) {
        const float* Xf = (const float*)Xv;
        for (int i = t; i < 64 * 32; i += 256) {
            int r = i >> 5, c4 = (i & 31) << 2;
            int gr = row0 + r;
            float4 v = (gr < N) ? *(const float4*)(Xf + (size_t)gr * F + c4)
                                : make_float4(0.f, 0.f, 0.f, 0.f);
            f16x4 h4 = {(_Float16)v.x, (_Float16)v.y, (_Float16)v.z, (_Float16)v.w};
            *(f16x4*)(xs + r * LDP + c4) = h4;
        }
    } else {
        const _Float16* Xh = (const _Float16*)Xv;
        for (int i = t; i < 64 * 16; i += 256) {
            int r = i >> 4, c8 = (i & 15) << 3;
            int gr = row0 + r;
            f16x8 v = {0, 0, 0, 0, 0, 0, 0, 0};
            if (gr < N) v = *(const f16x8*)(Xh + (size_t)gr * F + c8);
            *(f16x8*)(xs + r * LDP + c8) = v;
        }
    }
    __syncthreads();

    int w = t >> 6, lane = t & 63, q = lane >> 4, r = lane & 15;
    f32x4 acc[8] = {};
    const _Float16* xrow = xs + (w * 16 + r) * LDP;
    const _Float16* wrow = ws + r * LDP;
#pragma unroll
    for (int kk = 0; kk < 4; ++kk) {
        f16x8 bx = *(const f16x8*)(xrow + kk * 32 + q * 8);
#pragma unroll
        for (int nt = 0; nt < 8; ++nt) {
            f16x8 af = *(const f16x8*)(wrow + nt * 16 * LDP + kk * 32 + q * 8);
            acc[nt] = __builtin_amdgcn_mfma_f32_16x16x32_f16(af, bx, acc[nt], 0, 0, 0);
        }
    }
    int m = row0 + w * 16 + r;

    float sh[4], dh[4];
#pragma unroll
    for (int h = 0; h < 4; ++h) {
        float s = 0.f, d = 0.f;
#pragma unroll
        for (int k2 = 0; k2 < 2; ++k2) {
            int nt = h * 2 + k2;
            float4 av = ((const float4*)asrc)[nt * 4 + q];
            float4 bv = ((const float4*)adst)[nt * 4 + q];
            s += acc[nt][0] * av.x + acc[nt][1] * av.y + acc[nt][2] * av.z + acc[nt][3] * av.w;
            d += acc[nt][0] * bv.x + acc[nt][1] * bv.y + acc[nt][2] * bv.z + acc[nt][3] * bv.w;
        }
        s += __shfl_xor(s, 16); s += __shfl_xor(s, 32);
        d += __shfl_xor(d, 16); d += __shfl_xor(d, 32);
        sh[h] = s; dh[h] = d;
    }
    if (q == 0 && m < N) {
        ((float4*)As)[m] = make_float4(sh[0], sh[1], sh[2], sh[3]);
        ((float4*)Ad)[m] = make_float4(dh[0], dh[1], dh[2], dh[3]);
    }
    if (m < N) {
        _Float16* hp = Hh + (size_t)m * F + q * 4;
#pragma unroll
        for (int nt = 0; nt < 8; ++nt) {
            f16x4 h4 = {(_Float16)acc[nt][0], (_Float16)acc[nt][1],
                        (_Float16)acc[nt][2], (_Float16)acc[nt][3]};
            *(f16x4*)(hp + nt * 16) = h4;
        }
    }
}

// ---- scan: sum per-block hist slots, exclusive-scan edge & src counts ----
__global__ __launch_bounds__(NB) void k_bscan(const int* __restrict__ histSlots, int gB,
                                              int* __restrict__ bucketCnt,
                                              int* __restrict__ edgeStart,
                                              int* __restrict__ srcStart,
                                              int* __restrict__ bucketCursor,
                                              int* __restrict__ rowstart, int N) {
    __shared__ int ws1[4], ws2[4];
    int t = threadIdx.x, lane = t & 63, w = t >> 6;
    int c = 0;
    for (int i = 0; i < gB; ++i) c += histSlots[i * NB + t];
    bucketCnt[t] = c;
    int nIn = N - t * NPB; nIn = nIn < 0 ? 0 : (nIn > NPB ? NPB : nIn);
    int s = c + nIn;
    int x1 = c, x2 = s;
#pragma unroll
    for (int off = 1; off < 64; off <<= 1) {
        int a = __shfl_up(x1, off), b = __shfl_up(x2, off);
        if (lane >= off) { x1 += a; x2 += b; }
    }
    if (lane == 63) { ws1[w] = x1; ws2[w] = x2; }
    __syncthreads();
    int o1 = 0, o2 = 0;
    for (int i = 0; i < w; ++i) { o1 += ws1[i]; o2 += ws2[i]; }
    int e1 = o1 + x1 - c;
    int e2 = o2 + x2 - s;
    edgeStart[t] = e1; srcStart[t] = e2; bucketCursor[t] = e1;
    if (t == NB - 1) {
        edgeStart[NB] = e1 + c;
        srcStart[NB] = e2 + s;
        rowstart[N] = e2 + s;
    }
}

__global__ __launch_bounds__(256) void k_bscatter(const int* __restrict__ src,
                                                  const int* __restrict__ dst,
                                                  int* __restrict__ bucketCursor,
                                                  uint2* __restrict__ temp, int E) {
    __shared__ uint2 se[BE];
    __shared__ int hist[NB], lofs[NB], lcur[NB], gbase[NB];
    __shared__ int wsum[4];
    int t = threadIdx.x;
    hist[t] = 0;
    __syncthreads();
    int base = blockIdx.x * BE;
    int end = min(base + BE, E);
    for (int i = base + t; i < end; i += 256) atomicAdd(&hist[dst[i] / NPB], 1);
    __syncthreads();
    {
        int lane = t & 63, w = t >> 6;
        int c = hist[t], x = c;
#pragma unroll
        for (int off = 1; off < 64; off <<= 1) {
            int a = __shfl_up(x, off);
            if (lane >= off) x += a;
        }
        if (lane == 63) wsum[w] = x;
        __syncthreads();
        int o = 0;
        for (int i = 0; i < w; ++i) o += wsum[i];
        int ex = o + x - c;
        lofs[t] = ex;
        lcur[t] = ex;
        gbase[t] = c ? atomicAdd(&bucketCursor[t], c) : 0;
    }
    __syncthreads();
    for (int i = base + t; i < end; i += 256) {
        int d = dst[i];
        int b = d / NPB;
        int dl = d - b * NPB;
        int pos = atomicAdd(&lcur[b], 1);
        se[pos] = make_uint2((unsigned)src[i], (unsigned)((b << 8) | dl));
    }
    __syncthreads();
    int tot = end - base;
    for (int i = t; i < tot; i += 256) {
        uint2 e = se[i];
        int b = (int)(e.y >> 8);
        temp[gbase[b] + (i - lofs[b])] = e;
    }
}

__global__ __launch_bounds__(256) void k_bsort(const uint2* __restrict__ temp,
                                               const int* __restrict__ edgeStart,
                                               const int* __restrict__ srcStart,
                                               const int* __restrict__ bucketCnt,
                                               int* __restrict__ rowstart,
                                               int* __restrict__ srcs, int N) {
    __shared__ int cnt[NPB];
    __shared__ int scanE[NPB];
    __shared__ int outS[CAPS];
    __shared__ int wsum[4];
    int b = blockIdx.x, t = threadIdx.x;
    int eBase = edgeStart[b], eCnt = bucketCnt[b];
    int sBase = srcStart[b];
    int nIn = N - b * NPB; nIn = nIn < 0 ? 0 : (nIn > NPB ? NPB : nIn);
    for (int i = t; i < NPB; i += 256) cnt[i] = 1;
    __syncthreads();
    for (int i = t; i < eCnt; i += 256) {
        uint2 e = temp[eBase + i];
        atomicAdd(&cnt[e.y & 0xFF], 1);
    }
    __syncthreads();
    {
        int lane = t & 63, w = t >> 6;
        int c = (t < nIn) ? cnt[t] : 0;
        int x = c;
#pragma unroll
        for (int off = 1; off < 64; off <<= 1) {
            int a = __shfl_up(x, off);
            if (lane >= off) x += a;
        }
        if (lane == 63) wsum[w] = x;
        __syncthreads();
        int o = 0;
        for (int i = 0; i < w; ++i) o += wsum[i];
        if (t < nIn) scanE[t] = o + x - c;
    }
    __syncthreads();
    if (t < nIn) {
        int s0 = scanE[t];
        outS[s0] = b * NPB + t;
        cnt[t] = s0 + 1;
        rowstart[b * NPB + t] = sBase + s0;
    }
    __syncthreads();
    for (int i = t; i < eCnt; i += 256) {
        uint2 e = temp[eBase + i];
        int pos = atomicAdd(&cnt[e.y & 0xFF], 1);
        if (pos < CAPS) outS[pos] = (int)e.x;
    }
    __syncthreads();
    int tot = eCnt + nIn;
    for (int i = t; i < tot; i += 256) srcs[sBase + i] = outS[i];
}

// ---- fused softmax + gather + aggregate + bias (+relu): one wave per dst ----
// lane-group g=lane>>4 owns edges {j+g, j+4+g, ...}; 16 lanes x 16 B per edge.
// Main loop 16 edges/iter (4 loads in flight/lane); branchless 4-edge tail.
template <bool RELU, bool OUTH>
__global__ __launch_bounds__(256) void k_aggr(const int* __restrict__ rowstart,
                                              const int* __restrict__ srcs,
                                              const float* __restrict__ As,
                                              const float* __restrict__ Ad,
                                              const _Float16* __restrict__ Hh,
                                              const float* __restrict__ bias,
                                              void* __restrict__ Ov, int N) {
    __shared__ float exs_s[4][256];
    int wid = threadIdx.x >> 6;
    float* exs = exs_s[wid];
    int w = (blockIdx.x << 2) + wid;
    int lane = threadIdx.x & 63;
    if (w >= N) return;
    int d = w;
    int b0 = rowstart[d], b1 = rowstart[d + 1];
    int g = lane >> 4, l16 = lane & 15;
    int h = l16 >> 2;
    float4 ad4 = ((const float4*)Ad)[d];
    float den = 0.f;
    float acc[8] = {};

    for (int base = b0; base < b1; base += 64) {
        int cnt = min(64, b1 - base);
        int myv = (lane < cnt) ? srcs[base + lane] : 0;
        if (lane < cnt) {
            float4 a4 = ((const float4*)As)[myv];
            float4 e;
            e.x = __expf(lrelu(a4.x + ad4.x));
            e.y = __expf(lrelu(a4.y + ad4.y));
            e.z = __expf(lrelu(a4.z + ad4.z));
            e.w = __expf(lrelu(a4.w + ad4.w));
            ((float4*)exs)[lane] = e;
        }
        int j = 0;
        for (; j + 16 <= cnt; j += 16) {       // 16 edges/iter, 4 loads in flight
            int s0 = __shfl(myv, j + g);
            int s1 = __shfl(myv, j + 4 + g);
            int s2 = __shfl(myv, j + 8 + g);
            int s3 = __shfl(myv, j + 12 + g);
            float4 q0 = *(const float4*)(Hh + (size_t)s0 * F + 8 * l16);
            float4 q1 = *(const float4*)(Hh + (size_t)s1 * F + 8 * l16);
            float4 q2 = *(const float4*)(Hh + (size_t)s2 * F + 8 * l16);
            float4 q3 = *(const float4*)(Hh + (size_t)s3 * F + 8 * l16);
            float e0 = exs[(j + g) * 4 + h];
            float e1 = exs[(j + 4 + g) * 4 + h];
            float e2 = exs[(j + 8 + g) * 4 + h];
            float e3 = exs[(j + 12 + g) * 4 + h];
            den += (e0 + e1) + (e2 + e3);
            const __half2* p0 = (const __half2*)&q0;
            const __half2* p1 = (const __half2*)&q1;
            const __half2* p2 = (const __half2*)&q2;
            const __half2* p3 = (const __half2*)&q3;
#pragma unroll
            for (int u = 0; u < 4; ++u) {
                float2 f0 = __half22float2(p0[u]);
                float2 f1 = __half22float2(p1[u]);
                float2 f2 = __half22float2(p2[u]);
                float2 f3 = __half22float2(p3[u]);
                acc[2 * u]     += e0 * f0.x + e1 * f1.x + e2 * f2.x + e3 * f3.x;
                acc[2 * u + 1] += e0 * f0.y + e1 * f1.y + e2 * f2.y + e3 * f3.y;
            }
        }
        if (j + 8 <= cnt) {                    // one 8-edge step
            int s0 = __shfl(myv, j + g);
            int s1 = __shfl(myv, j + 4 + g);
            float4 q0 = *(const float4*)(Hh + (size_t)s0 * F + 8 * l16);
            float4 q1 = *(const float4*)(Hh + (size_t)s1 * F + 8 * l16);
            float e0 = exs[(j + g) * 4 + h];
            float e1 = exs[(j + 4 + g) * 4 + h];
            den += e0 + e1;
            const __half2* p0 = (const __half2*)&q0;
            const __half2* p1 = (const __half2*)&q1;
#pragma unroll
            for (int u = 0; u < 4; ++u) {
                float2 f0 = __half22float2(p0[u]);
                float2 f1 = __half22float2(p1[u]);
                acc[2 * u]     += e0 * f0.x + e1 * f1.x;
                acc[2 * u + 1] += e0 * f0.y + e1 * f1.y;
            }
            j += 8;
        }
        for (; j < cnt; j += 4) {              // branchless tail: 4 edges/iter
            int idx = j + g;
            bool ok = idx < cnt;
            int idxc = ok ? idx : (cnt - 1);
            int s0 = __shfl(myv, idxc);        // all 64 lanes active
            float e0 = ok ? exs[idx * 4 + h] : 0.f;
            float4 q0 = *(const float4*)(Hh + (size_t)s0 * F + 8 * l16);
            den += e0;
            const __half2* p0 = (const __half2*)&q0;
#pragma unroll
            for (int u = 0; u < 4; ++u) {
                float2 f0 = __half22float2(p0[u]);
                acc[2 * u]     += e0 * f0.x;
                acc[2 * u + 1] += e0 * f0.y;
            }
        }
    }
#pragma unroll
    for (int i = 0; i < 8; ++i) {
        acc[i] += __shfl_xor(acc[i], 16);
        acc[i] += __shfl_xor(acc[i], 32);
    }
    den += __shfl_xor(den, 16);
    den += __shfl_xor(den, 32);
    float inv = 1.f / (den + 1e-16f);

    if (g == 0) {
        float4 bv0 = ((const float4*)bias)[2 * l16];
        float4 bv1 = ((const float4*)bias)[2 * l16 + 1];
        float o[8];
        o[0] = acc[0] * inv + bv0.x; o[1] = acc[1] * inv + bv0.y;
        o[2] = acc[2] * inv + bv0.z; o[3] = acc[3] * inv + bv0.w;
        o[4] = acc[4] * inv + bv1.x; o[5] = acc[5] * inv + bv1.y;
        o[6] = acc[6] * inv + bv1.z; o[7] = acc[7] * inv + bv1.w;
        if (RELU) {
#pragma unroll
            for (int i = 0; i < 8; ++i) o[i] = fmaxf(o[i], 0.f);
        }
        if (OUTH) {
            f16x8 p;
#pragma unroll
            for (int i = 0; i < 8; ++i) p[i] = (_Float16)o[i];
            *(f16x8*)((_Float16*)Ov + (size_t)d * F + 8 * l16) = p;
        } else {
            float* op = (float*)Ov + (size_t)d * F + 8 * l16;
            *(float4*)op = make_float4(o[0], o[1], o[2], o[3]);
            *(float4*)(op + 4) = make_float4(o[4], o[5], o[6], o[7]);
        }
    }
}

extern "C" void kernel_launch(void* const* d_in, const int* in_sizes, int n_in,
                              void* d_out, int out_size, void* d_ws, size_t ws_size,
                              hipStream_t stream) {
    const float* x   = (const float*)d_in[0];
    const int*   ei  = (const int*)d_in[1];
    const float* W1  = (const float*)d_in[2];
    const float* as1 = (const float*)d_in[3];
    const float* ad1 = (const float*)d_in[4];
    const float* b1  = (const float*)d_in[5];
    const float* W2  = (const float*)d_in[6];
    const float* as2 = (const float*)d_in[7];
    const float* ad2 = (const float*)d_in[8];
    const float* b2  = (const float*)d_in[9];

    int N = in_sizes[0] / F;
    int E = in_sizes[1] / 2;
    const int* src = ei;
    const int* dst = ei + E;

    int gB = (E + BE - 1) / BE;

    char* base = (char*)d_ws;
    size_t off = 0;
    _Float16* Hh  = (_Float16*)(base + off); off += (size_t)N * F * 2;
    _Float16* O1h = (_Float16*)(base + off); off += (size_t)N * F * 2;
    float* As  = (float*)(base + off);  off += (size_t)N * HEADS * 4;
    float* Ad  = (float*)(base + off);  off += (size_t)N * HEADS * 4;
    int* rowstart = (int*)(base + off); off += (size_t)(N + 1) * 4;
    off = (off + 15) & ~(size_t)15;
    int* srcs = (int*)(base + off);     off += (size_t)(E + N) * 4;
    off = (off + 15) & ~(size_t)15;
    uint2* temp = (uint2*)(base + off); off += (size_t)E * 8;
    int* bucketCnt   = (int*)(base + off); off += NB * 4;
    int* edgeStart   = (int*)(base + off); off += (NB + 1) * 4;
    int* srcStart    = (int*)(base + off); off += (NB + 1) * 4;
    int* bucketCursor= (int*)(base + off); off += NB * 4;
    off = (off + 15) & ~(size_t)15;
    _Float16* Wt1 = (_Float16*)(base + off); off += 128 * 128 * 2;
    _Float16* Wt2 = (_Float16*)(base + off); off += 128 * 128 * 2;
    off = (off + 15) & ~(size_t)15;
    int* histSlots = (int*)(base + off); off += (size_t)gB * NB * 4;

    dim3 blk(256);
    int gG = (N + 63) / 64;
    int gW = (N + 3) / 4;

    // -------- weight cvt + per-block hist (merged), CSR build --------
    k_wcvt_hist<<<gB + 2, blk, 0, stream>>>(W1, W2, Wt1, Wt2, dst, histSlots, E, gB);
    k_bscan<<<1, NB, 0, stream>>>(histSlots, gB, bucketCnt, edgeStart, srcStart,
                                  bucketCursor, rowstart, N);
    k_bscatter<<<gB, blk, 0, stream>>>(src, dst, bucketCursor, temp, E);
    k_bsort<<<NB, blk, 0, stream>>>(temp, edgeStart, srcStart, bucketCnt, rowstart, srcs, N);

    // -------- layer 1 --------
    k_gemm_mfma<true><<<gG, blk, 0, stream>>>(x, Wt1, as1, ad1, Hh, As, Ad, N);
    k_aggr<true, true><<<gW, blk, 0, stream>>>(rowstart, srcs, As, Ad, Hh, b1, O1h, N);

    // -------- layer 2 --------
    k_gemm_mfma<false><<<gG, blk, 0, stream>>>(O1h, Wt2, as2, ad2, Hh, As, Ad, N);
    k_aggr<false, false><<<gW, blk, 0, stream>>>(rowstart, srcs, As, Ad, Hh, b2, d_out, N);
}

// Round 12
// 170.280 us; speedup vs baseline: 1.0343x; 1.0343x over previous
//
#include <hip/hip_runtime.h>
#include <hip/hip_fp16.h>

#define HEADS 4
#define F 128
#define NEG_SLOPE 0.2f

#define NB 256        // buckets
#define NPB 196       // nodes/bucket: NB*NPB = 50176 >= N
#define BE 8192       // edges per hist/bscatter block
#define CAPS 6144     // max (edges + self-loops) per bucket

#define LDP 136       // padded LDS row stride in halfs

typedef _Float16 f16x8 __attribute__((ext_vector_type(8)));
typedef _Float16 f16x4 __attribute__((ext_vector_type(4)));
typedef float f32x4 __attribute__((ext_vector_type(4)));

__device__ __forceinline__ float lrelu(float v) { return v > 0.f ? v : NEG_SLOPE * v; }

// ---- merged: blocks 0..gB-1 per-block histogram (plain stores); blocks
//      gB..gB+1 convert W -> Wt fp16 [n][k] ----
__global__ __launch_bounds__(256) void k_wcvt_hist(const float* __restrict__ W1,
                                                   const float* __restrict__ W2,
                                                   _Float16* __restrict__ Wt1,
                                                   _Float16* __restrict__ Wt2,
                                                   const int* __restrict__ dst,
                                                   int* __restrict__ histSlots,
                                                   int E, int gB) {
    __shared__ _Float16 l[128][LDP];
    __shared__ int hh[NB];
    int t = threadIdx.x;
    int bx = blockIdx.x;
    if (bx >= gB) {                      // weight convert+transpose
        const float* W = (bx - gB) ? W2 : W1;
        _Float16* Wt = (bx - gB) ? Wt2 : Wt1;
        for (int i = t; i < 4096; i += 256) {
            int k = i >> 5, n4 = (i & 31) << 2;
            float4 v = ((const float4*)W)[i];
            l[n4][k]     = (_Float16)v.x;
            l[n4 + 1][k] = (_Float16)v.y;
            l[n4 + 2][k] = (_Float16)v.z;
            l[n4 + 3][k] = (_Float16)v.w;
        }
        __syncthreads();
        for (int i = t; i < 2048; i += 256) {
            int n = i >> 4, c8 = (i & 15) << 3;
            *(f16x8*)(Wt + n * 128 + c8) = *(const f16x8*)(&l[n][c8]);
        }
        return;
    }
    hh[t] = 0;
    __syncthreads();
    int base = bx * BE;
    int end = min(base + BE, E);
    for (int i = base + t; i < end; i += 256) atomicAdd(&hh[dst[i] / NPB], 1);
    __syncthreads();
    histSlots[bx * NB + t] = hh[t];      // every slot written every call
}

// ---- MFMA GEMM + fused logits: h^T = Wt * X^T ; Hh fp16 ; As/Ad from fp32 acc ----
template <bool FP32IN>
__global__ __launch_bounds__(256) void k_gemm_mfma(const void* __restrict__ Xv,
                                                   const _Float16* __restrict__ Wt,
                                                   const float* __restrict__ asrc,
                                                   const float* __restrict__ adst,
                                                   _Float16* __restrict__ Hh,
                                                   float* __restrict__ As,
                                                   float* __restrict__ Ad, int N) {
    __shared__ _Float16 xs[64 * LDP];
    __shared__ _Float16 ws[128 * LDP];
    int t = threadIdx.x;
    int row0 = blockIdx.x * 64;

    for (int i = t; i < 128 * 16; i += 256) {
        int rw = i >> 4, c8 = (i & 15) << 3;
        *(f16x8*)(ws + rw * LDP + c8) = *(const f16x8*)(Wt + rw * 128 + c8);
    }
    if (FP32IN) {
        const float* Xf = (const float*)Xv;
        for (int i = t; i < 64 * 32; i += 256) {
            int r = i >> 5, c4 = (i & 31) << 2;
            int gr = row0 + r;
            float4 v = (gr < N) ? *(const float4*)(Xf + (size_t)gr * F + c4)
                                : make_float4(0.f, 0.f, 0.f, 0.f);
            f16x4 h4 = {(_Float16)v.x, (_Float16)v.y, (_Float16)v.z, (_Float16)v.w};
            *(f16x4*)(xs + r * LDP + c4) = h4;
        }
    } else {
        const _Float16* Xh = (const _Float16*)Xv;
        for (int i = t; i < 64 * 16; i += 256) {
            int r = i >> 4, c8 = (i & 15) << 3;
            int gr = row0 + r;
            f16x8 v = {0, 0, 0, 0, 0, 0, 0, 0};
            if (gr < N) v = *(const f16x8*)(Xh + (size_t)gr * F + c8);
            *(f16x8*)(xs + r * LDP + c8) = v;
        }
    }
    __syncthreads();

    int w = t >> 6, lane = t & 63, q = lane >> 4, r = lane & 15;
    f32x4 acc[8] = {};
    const _Float16* xrow = xs + (w * 16 + r) * LDP;
    const _Float16* wrow = ws + r * LDP;
#pragma unroll
    for (int kk = 0; kk < 4; ++kk) {
        f16x8 bx = *(const f16x8*)(xrow + kk * 32 + q * 8);
#pragma unroll
        for (int nt = 0; nt < 8; ++nt) {
            f16x8 af = *(const f16x8*)(wrow + nt * 16 * LDP + kk * 32 + q * 8);
            acc[nt] = __builtin_amdgcn_mfma_f32_16x16x32_f16(af, bx, acc[nt], 0, 0, 0);
        }
    }
    int m = row0 + w * 16 + r;

    float sh[4], dh[4];
#pragma unroll
    for (int h = 0; h < 4; ++h) {
        float s = 0.f, d = 0.f;
#pragma unroll
        for (int k2 = 0; k2 < 2; ++k2) {
            int nt = h * 2 + k2;
            float4 av = ((const float4*)asrc)[nt * 4 + q];
            float4 bv = ((const float4*)adst)[nt * 4 + q];
            s += acc[nt][0] * av.x + acc[nt][1] * av.y + acc[nt][2] * av.z + acc[nt][3] * av.w;
            d += acc[nt][0] * bv.x + acc[nt][1] * bv.y + acc[nt][2] * bv.z + acc[nt][3] * bv.w;
        }
        s += __shfl_xor(s, 16); s += __shfl_xor(s, 32);
        d += __shfl_xor(d, 16); d += __shfl_xor(d, 32);
        sh[h] = s; dh[h] = d;
    }
    if (q == 0 && m < N) {
        ((float4*)As)[m] = make_float4(sh[0], sh[1], sh[2], sh[3]);
        ((float4*)Ad)[m] = make_float4(dh[0], dh[1], dh[2], dh[3]);
    }
    if (m < N) {
        _Float16* hp = Hh + (size_t)m * F + q * 4;
#pragma unroll
        for (int nt = 0; nt < 8; ++nt) {
            f16x4 h4 = {(_Float16)acc[nt][0], (_Float16)acc[nt][1],
                        (_Float16)acc[nt][2], (_Float16)acc[nt][3]};
            *(f16x4*)(hp + nt * 16) = h4;
        }
    }
}

// ---- scan: sum per-block hist slots, exclusive-scan edge & src counts ----
__global__ __launch_bounds__(NB) void k_bscan(const int* __restrict__ histSlots, int gB,
                                              int* __restrict__ bucketCnt,
                                              int* __restrict__ edgeStart,
                                              int* __restrict__ srcStart,
                                              int* __restrict__ bucketCursor,
                                              int* __restrict__ rowstart, int N) {
    __shared__ int ws1[4], ws2[4];
    int t = threadIdx.x, lane = t & 63, w = t >> 6;
    int c = 0;
    for (int i = 0; i < gB; ++i) c += histSlots[i * NB + t];
    bucketCnt[t] = c;
    int nIn = N - t * NPB; nIn = nIn < 0 ? 0 : (nIn > NPB ? NPB : nIn);
    int s = c + nIn;
    int x1 = c, x2 = s;
#pragma unroll
    for (int off = 1; off < 64; off <<= 1) {
        int a = __shfl_up(x1, off), b = __shfl_up(x2, off);
        if (lane >= off) { x1 += a; x2 += b; }
    }
    if (lane == 63) { ws1[w] = x1; ws2[w] = x2; }
    __syncthreads();
    int o1 = 0, o2 = 0;
    for (int i = 0; i < w; ++i) { o1 += ws1[i]; o2 += ws2[i]; }
    int e1 = o1 + x1 - c;
    int e2 = o2 + x2 - s;
    edgeStart[t] = e1; srcStart[t] = e2; bucketCursor[t] = e1;
    if (t == NB - 1) {
        edgeStart[NB] = e1 + c;
        srcStart[NB] = e2 + s;
        rowstart[N] = e2 + s;
    }
}

__global__ __launch_bounds__(256) void k_bscatter(const int* __restrict__ src,
                                                  const int* __restrict__ dst,
                                                  int* __restrict__ bucketCursor,
                                                  uint2* __restrict__ temp, int E) {
    __shared__ uint2 se[BE];
    __shared__ int hist[NB], lofs[NB], lcur[NB], gbase[NB];
    __shared__ int wsum[4];
    int t = threadIdx.x;
    hist[t] = 0;
    __syncthreads();
    int base = blockIdx.x * BE;
    int end = min(base + BE, E);
    for (int i = base + t; i < end; i += 256) atomicAdd(&hist[dst[i] / NPB], 1);
    __syncthreads();
    {
        int lane = t & 63, w = t >> 6;
        int c = hist[t], x = c;
#pragma unroll
        for (int off = 1; off < 64; off <<= 1) {
            int a = __shfl_up(x, off);
            if (lane >= off) x += a;
        }
        if (lane == 63) wsum[w] = x;
        __syncthreads();
        int o = 0;
        for (int i = 0; i < w; ++i) o += wsum[i];
        int ex = o + x - c;
        lofs[t] = ex;
        lcur[t] = ex;
        gbase[t] = c ? atomicAdd(&bucketCursor[t], c) : 0;
    }
    __syncthreads();
    for (int i = base + t; i < end; i += 256) {
        int d = dst[i];
        int b = d / NPB;
        int dl = d - b * NPB;
        int pos = atomicAdd(&lcur[b], 1);
        se[pos] = make_uint2((unsigned)src[i], (unsigned)((b << 8) | dl));
    }
    __syncthreads();
    int tot = end - base;
    for (int i = t; i < tot; i += 256) {
        uint2 e = se[i];
        int b = (int)(e.y >> 8);
        temp[gbase[b] + (i - lofs[b])] = e;
    }
}

__global__ __launch_bounds__(256) void k_bsort(const uint2* __restrict__ temp,
                                               const int* __restrict__ edgeStart,
                                               const int* __restrict__ srcStart,
                                               const int* __restrict__ bucketCnt,
                                               int* __restrict__ rowstart,
                                               int* __restrict__ srcs, int N) {
    __shared__ int cnt[NPB];
    __shared__ int scanE[NPB];
    __shared__ int outS[CAPS];
    __shared__ int wsum[4];
    int b = blockIdx.x, t = threadIdx.x;
    int eBase = edgeStart[b], eCnt = bucketCnt[b];
    int sBase = srcStart[b];
    int nIn = N - b * NPB; nIn = nIn < 0 ? 0 : (nIn > NPB ? NPB : nIn);
    for (int i = t; i < NPB; i += 256) cnt[i] = 1;
    __syncthreads();
    for (int i = t; i < eCnt; i += 256) {
        uint2 e = temp[eBase + i];
        atomicAdd(&cnt[e.y & 0xFF], 1);
    }
    __syncthreads();
    {
        int lane = t & 63, w = t >> 6;
        int c = (t < nIn) ? cnt[t] : 0;
        int x = c;
#pragma unroll
        for (int off = 1; off < 64; off <<= 1) {
            int a = __shfl_up(x, off);
            if (lane >= off) x += a;
        }
        if (lane == 63) wsum[w] = x;
        __syncthreads();
        int o = 0;
        for (int i = 0; i < w; ++i) o += wsum[i];
        if (t < nIn) scanE[t] = o + x - c;
    }
    __syncthreads();
    if (t < nIn) {
        int s0 = scanE[t];
        outS[s0] = b * NPB + t;
        cnt[t] = s0 + 1;
        rowstart[b * NPB + t] = sBase + s0;
    }
    __syncthreads();
    for (int i = t; i < eCnt; i += 256) {
        uint2 e = temp[eBase + i];
        int pos = atomicAdd(&cnt[e.y & 0xFF], 1);
        if (pos < CAPS) outS[pos] = (int)e.x;
    }
    __syncthreads();
    int tot = eCnt + nIn;
    for (int i = t; i < tot; i += 256) srcs[sBase + i] = outS[i];
}

// ---- fused softmax + gather + aggregate + bias (+relu): one wave per dst ----
// lane-group g=lane>>4 owns edge j+g; each of its 16 lanes loads 16 B (8 feats).
// Round-10 proven shape: 8-edge main loop + branchless 4-edge tail (VGPR 28).
template <bool RELU, bool OUTH>
__global__ __launch_bounds__(256) void k_aggr(const int* __restrict__ rowstart,
                                              const int* __restrict__ srcs,
                                              const float* __restrict__ As,
                                              const float* __restrict__ Ad,
                                              const _Float16* __restrict__ Hh,
                                              const float* __restrict__ bias,
                                              void* __restrict__ Ov, int N) {
    __shared__ float exs_s[4][256];
    int wid = threadIdx.x >> 6;
    float* exs = exs_s[wid];
    int w = (blockIdx.x << 2) + wid;
    int lane = threadIdx.x & 63;
    if (w >= N) return;
    int d = w;
    int b0 = rowstart[d], b1 = rowstart[d + 1];
    int g = lane >> 4, l16 = lane & 15;
    int h = l16 >> 2;                  // head of this lane's 8 features
    float4 ad4 = ((const float4*)Ad)[d];
    float den = 0.f;
    float acc[8] = {};

    for (int base = b0; base < b1; base += 64) {
        int cnt = min(64, b1 - base);
        int myv = (lane < cnt) ? srcs[base + lane] : 0;
        if (lane < cnt) {              // stage exp for all 4 heads of my edge
            float4 a4 = ((const float4*)As)[myv];
            float4 e;
            e.x = __expf(lrelu(a4.x + ad4.x));
            e.y = __expf(lrelu(a4.y + ad4.y));
            e.z = __expf(lrelu(a4.z + ad4.z));
            e.w = __expf(lrelu(a4.w + ad4.w));
            ((float4*)exs)[lane] = e;
        }
        int j = 0;
        for (; j + 8 <= cnt; j += 8) {     // 8 edges/iter: 2 per lane-group
            int s0 = __shfl(myv, j + g);
            int s1 = __shfl(myv, j + 4 + g);
            float4 q0 = *(const float4*)(Hh + (size_t)s0 * F + 8 * l16);
            float4 q1 = *(const float4*)(Hh + (size_t)s1 * F + 8 * l16);
            float e0 = exs[(j + g) * 4 + h];
            float e1 = exs[(j + 4 + g) * 4 + h];
            den += e0 + e1;
            const __half2* p0 = (const __half2*)&q0;
            const __half2* p1 = (const __half2*)&q1;
#pragma unroll
            for (int u = 0; u < 4; ++u) {
                float2 f0 = __half22float2(p0[u]);
                float2 f1 = __half22float2(p1[u]);
                acc[2 * u]     += e0 * f0.x + e1 * f1.x;
                acc[2 * u + 1] += e0 * f0.y + e1 * f1.y;
            }
        }
        for (; j < cnt; j += 4) {          // branchless tail: 4 edges/iter
            int idx = j + g;
            bool ok = idx < cnt;
            int idxc = ok ? idx : (cnt - 1);
            int s0 = __shfl(myv, idxc);    // all 64 lanes active; src lane active
            float e0 = ok ? exs[idx * 4 + h] : 0.f;
            float4 q0 = *(const float4*)(Hh + (size_t)s0 * F + 8 * l16);
            den += e0;
            const __half2* p0 = (const __half2*)&q0;
#pragma unroll
            for (int u = 0; u < 4; ++u) {
                float2 f0 = __half22float2(p0[u]);
                acc[2 * u]     += e0 * f0.x;
                acc[2 * u + 1] += e0 * f0.y;
            }
        }
    }
#pragma unroll
    for (int i = 0; i < 8; ++i) {
        acc[i] += __shfl_xor(acc[i], 16);
        acc[i] += __shfl_xor(acc[i], 32);
    }
    den += __shfl_xor(den, 16);
    den += __shfl_xor(den, 32);
    float inv = 1.f / (den + 1e-16f);

    if (g == 0) {
        float4 bv0 = ((const float4*)bias)[2 * l16];
        float4 bv1 = ((const float4*)bias)[2 * l16 + 1];
        float o[8];
        o[0] = acc[0] * inv + bv0.x; o[1] = acc[1] * inv + bv0.y;
        o[2] = acc[2] * inv + bv0.z; o[3] = acc[3] * inv + bv0.w;
        o[4] = acc[4] * inv + bv1.x; o[5] = acc[5] * inv + bv1.y;
        o[6] = acc[6] * inv + bv1.z; o[7] = acc[7] * inv + bv1.w;
        if (RELU) {
#pragma unroll
            for (int i = 0; i < 8; ++i) o[i] = fmaxf(o[i], 0.f);
        }
        if (OUTH) {
            f16x8 p;
#pragma unroll
            for (int i = 0; i < 8; ++i) p[i] = (_Float16)o[i];
            *(f16x8*)((_Float16*)Ov + (size_t)d * F + 8 * l16) = p;
        } else {
            float* op = (float*)Ov + (size_t)d * F + 8 * l16;
            *(float4*)op = make_float4(o[0], o[1], o[2], o[3]);
            *(float4*)(op + 4) = make_float4(o[4], o[5], o[6], o[7]);
        }
    }
}

extern "C" void kernel_launch(void* const* d_in, const int* in_sizes, int n_in,
                              void* d_out, int out_size, void* d_ws, size_t ws_size,
                              hipStream_t stream) {
    const float* x   = (const float*)d_in[0];
    const int*   ei  = (const int*)d_in[1];
    const float* W1  = (const float*)d_in[2];
    const float* as1 = (const float*)d_in[3];
    const float* ad1 = (const float*)d_in[4];
    const float* b1  = (const float*)d_in[5];
    const float* W2  = (const float*)d_in[6];
    const float* as2 = (const float*)d_in[7];
    const float* ad2 = (const float*)d_in[8];
    const float* b2  = (const float*)d_in[9];

    int N = in_sizes[0] / F;
    int E = in_sizes[1] / 2;
    const int* src = ei;
    const int* dst = ei + E;

    int gB = (E + BE - 1) / BE;

    char* base = (char*)d_ws;
    size_t off = 0;
    _Float16* Hh  = (_Float16*)(base + off); off += (size_t)N * F * 2;
    _Float16* O1h = (_Float16*)(base + off); off += (size_t)N * F * 2;
    float* As  = (float*)(base + off);  off += (size_t)N * HEADS * 4;
    float* Ad  = (float*)(base + off);  off += (size_t)N * HEADS * 4;
    int* rowstart = (int*)(base + off); off += (size_t)(N + 1) * 4;
    off = (off + 15) & ~(size_t)15;
    int* srcs = (int*)(base + off);     off += (size_t)(E + N) * 4;
    off = (off + 15) & ~(size_t)15;
    uint2* temp = (uint2*)(base + off); off += (size_t)E * 8;
    int* bucketCnt   = (int*)(base + off); off += NB * 4;
    int* edgeStart   = (int*)(base + off); off += (NB + 1) * 4;
    int* srcStart    = (int*)(base + off); off += (NB + 1) * 4;
    int* bucketCursor= (int*)(base + off); off += NB * 4;
    off = (off + 15) & ~(size_t)15;
    _Float16* Wt1 = (_Float16*)(base + off); off += 128 * 128 * 2;
    _Float16* Wt2 = (_Float16*)(base + off); off += 128 * 128 * 2;
    off = (off + 15) & ~(size_t)15;
    int* histSlots = (int*)(base + off); off += (size_t)gB * NB * 4;

    dim3 blk(256);
    int gG = (N + 63) / 64;
    int gW = (N + 3) / 4;

    // -------- weight cvt + per-block hist (merged), CSR build --------
    k_wcvt_hist<<<gB + 2, blk, 0, stream>>>(W1, W2, Wt1, Wt2, dst, histSlots, E, gB);
    k_bscan<<<1, NB, 0, stream>>>(histSlots, gB, bucketCnt, edgeStart, srcStart,
                                  bucketCursor, rowstart, N);
    k_bscatter<<<gB, blk, 0, stream>>>(src, dst, bucketCursor, temp, E);
    k_bsort<<<NB, blk, 0, stream>>>(temp, edgeStart, srcStart, bucketCnt, rowstart, srcs, N);

    // -------- layer 1 --------
    k_gemm_mfma<true><<<gG, blk, 0, stream>>>(x, Wt1, as1, ad1, Hh, As, Ad, N);
    k_aggr<true, true><<<gW, blk, 0, stream>>>(rowstart, srcs, As, Ad, Hh, b1, O1h, N);

    // -------- layer 2 --------
    k_gemm_mfma<false><<<gG, blk, 0, stream>>>(O1h, Wt2, as2, ad2, Hh, As, Ad, N);
    k_aggr<false, false><<<gW, blk, 0, stream>>>(rowstart, srcs, As, Ad, Hh, b2, d_out, N);
}

// Round 13
// 158.715 us; speedup vs baseline: 1.1097x; 1.0729x over previous
//
#include <hip/hip_runtime.h>
#include <hip/hip_fp16.h>

#define HEADS 4
#define F 128
#define NEG_SLOPE 0.2f

#define NB 256        // buckets
#define NPB 196       // nodes/bucket: NB*NPB = 50176 >= N
#define BE 5888       // edges per hist/bscatter block (sized so scatter LDS <= gemm LDS)
#define CAPS 6144     // max (edges + self-loops) per bucket

#define LDP 136       // padded LDS row stride in halfs
#define SMEM_BYTES 52224   // max(scatter: BE*8+4*NB*4+16 = 51216, gemm: (64+128)*LDP*2 = 52224)

typedef _Float16 f16x8 __attribute__((ext_vector_type(8)));
typedef _Float16 f16x4 __attribute__((ext_vector_type(4)));
typedef float f32x4 __attribute__((ext_vector_type(4)));

__device__ __forceinline__ float lrelu(float v) { return v > 0.f ? v : NEG_SLOPE * v; }

// ---- merged: blocks 0..gB-1 per-block histogram (plain stores); blocks
//      gB..gB+1 convert W -> Wt fp16 [n][k] ----
__global__ __launch_bounds__(256) void k_wcvt_hist(const float* __restrict__ W1,
                                                   const float* __restrict__ W2,
                                                   _Float16* __restrict__ Wt1,
                                                   _Float16* __restrict__ Wt2,
                                                   const int* __restrict__ dst,
                                                   int* __restrict__ histSlots,
                                                   int E, int gB) {
    __shared__ _Float16 l[128][LDP];
    __shared__ int hh[NB];
    int t = threadIdx.x;
    int bx = blockIdx.x;
    if (bx >= gB) {                      // weight convert+transpose
        const float* W = (bx - gB) ? W2 : W1;
        _Float16* Wt = (bx - gB) ? Wt2 : Wt1;
        for (int i = t; i < 4096; i += 256) {
            int k = i >> 5, n4 = (i & 31) << 2;
            float4 v = ((const float4*)W)[i];
            l[n4][k]     = (_Float16)v.x;
            l[n4 + 1][k] = (_Float16)v.y;
            l[n4 + 2][k] = (_Float16)v.z;
            l[n4 + 3][k] = (_Float16)v.w;
        }
        __syncthreads();
        for (int i = t; i < 2048; i += 256) {
            int n = i >> 4, c8 = (i & 15) << 3;
            *(f16x8*)(Wt + n * 128 + c8) = *(const f16x8*)(&l[n][c8]);
        }
        return;
    }
    hh[t] = 0;
    __syncthreads();
    int base = bx * BE;
    int end = min(base + BE, E);
    for (int i = base + t; i < end; i += 256) atomicAdd(&hh[dst[i] / NPB], 1);
    __syncthreads();
    histSlots[bx * NB + t] = hh[t];      // every slot written every call
}

// ---- scan: sum per-block hist slots, exclusive-scan edge & src counts ----
__global__ __launch_bounds__(NB) void k_bscan(const int* __restrict__ histSlots, int gB,
                                              int* __restrict__ bucketCnt,
                                              int* __restrict__ edgeStart,
                                              int* __restrict__ srcStart,
                                              int* __restrict__ bucketCursor,
                                              int* __restrict__ rowstart, int N) {
    __shared__ int ws1[4], ws2[4];
    int t = threadIdx.x, lane = t & 63, w = t >> 6;
    int c = 0;
    for (int i = 0; i < gB; ++i) c += histSlots[i * NB + t];
    bucketCnt[t] = c;
    int nIn = N - t * NPB; nIn = nIn < 0 ? 0 : (nIn > NPB ? NPB : nIn);
    int s = c + nIn;
    int x1 = c, x2 = s;
#pragma unroll
    for (int off = 1; off < 64; off <<= 1) {
        int a = __shfl_up(x1, off), b = __shfl_up(x2, off);
        if (lane >= off) { x1 += a; x2 += b; }
    }
    if (lane == 63) { ws1[w] = x1; ws2[w] = x2; }
    __syncthreads();
    int o1 = 0, o2 = 0;
    for (int i = 0; i < w; ++i) { o1 += ws1[i]; o2 += ws2[i]; }
    int e1 = o1 + x1 - c;
    int e2 = o2 + x2 - s;
    edgeStart[t] = e1; srcStart[t] = e2; bucketCursor[t] = e1;
    if (t == NB - 1) {
        edgeStart[NB] = e1 + c;
        srcStart[NB] = e2 + s;
        rowstart[N] = e2 + s;
    }
}

// ---- role-split fat kernel: blocks [0,gB) = bucket scatter; [gB,gB+gG) =
//      layer-1 MFMA GEMM (fp32 input) + fused attention logits.  Independent
//      work overlapped across CUs in ONE dispatch; LDS is a union.
__global__ __launch_bounds__(256) void k_scat_gemm(const int* __restrict__ src,
                                                   const int* __restrict__ dst,
                                                   int* __restrict__ bucketCursor,
                                                   uint2* __restrict__ temp, int E, int gB,
                                                   const float* __restrict__ X,
                                                   const _Float16* __restrict__ Wt,
                                                   const float* __restrict__ asrc,
                                                   const float* __restrict__ adst,
                                                   _Float16* __restrict__ Hh,
                                                   float* __restrict__ As,
                                                   float* __restrict__ Ad, int N) {
    __shared__ __align__(16) char smem[SMEM_BYTES];
    int t = threadIdx.x;
    int bx = blockIdx.x;

    if (bx < gB) {
        // ---------------- bscatter role ----------------
        uint2* se   = (uint2*)smem;                    // BE*8 = 47104 B
        int* hist   = (int*)(smem + BE * 8);           // 4*NB ints = 4 KB
        int* lofs   = hist + NB;
        int* lcur   = lofs + NB;
        int* gbase  = lcur + NB;
        int* wsum   = gbase + NB;                      // 4 ints
        hist[t] = 0;
        __syncthreads();
        int base = bx * BE;
        int end = min(base + BE, E);
        for (int i = base + t; i < end; i += 256) atomicAdd(&hist[dst[i] / NPB], 1);
        __syncthreads();
        {
            int lane = t & 63, w = t >> 6;
            int c = hist[t], x = c;
#pragma unroll
            for (int off = 1; off < 64; off <<= 1) {
                int a = __shfl_up(x, off);
                if (lane >= off) x += a;
            }
            if (lane == 63) wsum[w] = x;
            __syncthreads();
            int o = 0;
            for (int i = 0; i < w; ++i) o += wsum[i];
            int ex = o + x - c;
            lofs[t] = ex;
            lcur[t] = ex;
            gbase[t] = c ? atomicAdd(&bucketCursor[t], c) : 0;
        }
        __syncthreads();
        for (int i = base + t; i < end; i += 256) {
            int d = dst[i];
            int b = d / NPB;
            int dl = d - b * NPB;
            int pos = atomicAdd(&lcur[b], 1);
            se[pos] = make_uint2((unsigned)src[i], (unsigned)((b << 8) | dl));
        }
        __syncthreads();
        int tot = end - base;
        for (int i = t; i < tot; i += 256) {
            uint2 e = se[i];
            int b = (int)(e.y >> 8);
            temp[gbase[b] + (i - lofs[b])] = e;
        }
        return;
    }

    // ---------------- gemm role (layer 1, fp32 input) ----------------
    _Float16* xs = (_Float16*)smem;                    // 64*LDP halfs
    _Float16* ws = xs + 64 * LDP;                      // 128*LDP halfs
    int row0 = (bx - gB) * 64;

    for (int i = t; i < 128 * 16; i += 256) {
        int rw = i >> 4, c8 = (i & 15) << 3;
        *(f16x8*)(ws + rw * LDP + c8) = *(const f16x8*)(Wt + rw * 128 + c8);
    }
    for (int i = t; i < 64 * 32; i += 256) {
        int r = i >> 5, c4 = (i & 31) << 2;
        int gr = row0 + r;
        float4 v = (gr < N) ? *(const float4*)(X + (size_t)gr * F + c4)
                            : make_float4(0.f, 0.f, 0.f, 0.f);
        f16x4 h4 = {(_Float16)v.x, (_Float16)v.y, (_Float16)v.z, (_Float16)v.w};
        *(f16x4*)(xs + r * LDP + c4) = h4;
    }
    __syncthreads();

    int w = t >> 6, lane = t & 63, q = lane >> 4, r = lane & 15;
    f32x4 acc[8] = {};
    const _Float16* xrow = xs + (w * 16 + r) * LDP;
    const _Float16* wrow = ws + r * LDP;
#pragma unroll
    for (int kk = 0; kk < 4; ++kk) {
        f16x8 bxv = *(const f16x8*)(xrow + kk * 32 + q * 8);
#pragma unroll
        for (int nt = 0; nt < 8; ++nt) {
            f16x8 af = *(const f16x8*)(wrow + nt * 16 * LDP + kk * 32 + q * 8);
            acc[nt] = __builtin_amdgcn_mfma_f32_16x16x32_f16(af, bxv, acc[nt], 0, 0, 0);
        }
    }
    int m = row0 + w * 16 + r;

    float sh[4], dh[4];
#pragma unroll
    for (int h = 0; h < 4; ++h) {
        float s = 0.f, d = 0.f;
#pragma unroll
        for (int k2 = 0; k2 < 2; ++k2) {
            int nt = h * 2 + k2;
            float4 av = ((const float4*)asrc)[nt * 4 + q];
            float4 bv = ((const float4*)adst)[nt * 4 + q];
            s += acc[nt][0] * av.x + acc[nt][1] * av.y + acc[nt][2] * av.z + acc[nt][3] * av.w;
            d += acc[nt][0] * bv.x + acc[nt][1] * bv.y + acc[nt][2] * bv.z + acc[nt][3] * bv.w;
        }
        s += __shfl_xor(s, 16); s += __shfl_xor(s, 32);
        d += __shfl_xor(d, 16); d += __shfl_xor(d, 32);
        sh[h] = s; dh[h] = d;
    }
    if (q == 0 && m < N) {
        ((float4*)As)[m] = make_float4(sh[0], sh[1], sh[2], sh[3]);
        ((float4*)Ad)[m] = make_float4(dh[0], dh[1], dh[2], dh[3]);
    }
    if (m < N) {
        _Float16* hp = Hh + (size_t)m * F + q * 4;
#pragma unroll
        for (int nt = 0; nt < 8; ++nt) {
            f16x4 h4 = {(_Float16)acc[nt][0], (_Float16)acc[nt][1],
                        (_Float16)acc[nt][2], (_Float16)acc[nt][3]};
            *(f16x4*)(hp + nt * 16) = h4;
        }
    }
}

// ---- standalone MFMA GEMM (layer 2, fp16 input) + fused logits ----
__global__ __launch_bounds__(256) void k_gemm_mfma(const _Float16* __restrict__ Xh,
                                                   const _Float16* __restrict__ Wt,
                                                   const float* __restrict__ asrc,
                                                   const float* __restrict__ adst,
                                                   _Float16* __restrict__ Hh,
                                                   float* __restrict__ As,
                                                   float* __restrict__ Ad, int N) {
    __shared__ _Float16 xs[64 * LDP];
    __shared__ _Float16 ws[128 * LDP];
    int t = threadIdx.x;
    int row0 = blockIdx.x * 64;

    for (int i = t; i < 128 * 16; i += 256) {
        int rw = i >> 4, c8 = (i & 15) << 3;
        *(f16x8*)(ws + rw * LDP + c8) = *(const f16x8*)(Wt + rw * 128 + c8);
    }
    for (int i = t; i < 64 * 16; i += 256) {
        int r = i >> 4, c8 = (i & 15) << 3;
        int gr = row0 + r;
        f16x8 v = {0, 0, 0, 0, 0, 0, 0, 0};
        if (gr < N) v = *(const f16x8*)(Xh + (size_t)gr * F + c8);
        *(f16x8*)(xs + r * LDP + c8) = v;
    }
    __syncthreads();

    int w = t >> 6, lane = t & 63, q = lane >> 4, r = lane & 15;
    f32x4 acc[8] = {};
    const _Float16* xrow = xs + (w * 16 + r) * LDP;
    const _Float16* wrow = ws + r * LDP;
#pragma unroll
    for (int kk = 0; kk < 4; ++kk) {
        f16x8 bxv = *(const f16x8*)(xrow + kk * 32 + q * 8);
#pragma unroll
        for (int nt = 0; nt < 8; ++nt) {
            f16x8 af = *(const f16x8*)(wrow + nt * 16 * LDP + kk * 32 + q * 8);
            acc[nt] = __builtin_amdgcn_mfma_f32_16x16x32_f16(af, bxv, acc[nt], 0, 0, 0);
        }
    }
    int m = row0 + w * 16 + r;

    float sh[4], dh[4];
#pragma unroll
    for (int h = 0; h < 4; ++h) {
        float s = 0.f, d = 0.f;
#pragma unroll
        for (int k2 = 0; k2 < 2; ++k2) {
            int nt = h * 2 + k2;
            float4 av = ((const float4*)asrc)[nt * 4 + q];
            float4 bv = ((const float4*)adst)[nt * 4 + q];
            s += acc[nt][0] * av.x + acc[nt][1] * av.y + acc[nt][2] * av.z + acc[nt][3] * av.w;
            d += acc[nt][0] * bv.x + acc[nt][1] * bv.y + acc[nt][2] * bv.z + acc[nt][3] * bv.w;
        }
        s += __shfl_xor(s, 16); s += __shfl_xor(s, 32);
        d += __shfl_xor(d, 16); d += __shfl_xor(d, 32);
        sh[h] = s; dh[h] = d;
    }
    if (q == 0 && m < N) {
        ((float4*)As)[m] = make_float4(sh[0], sh[1], sh[2], sh[3]);
        ((float4*)Ad)[m] = make_float4(dh[0], dh[1], dh[2], dh[3]);
    }
    if (m < N) {
        _Float16* hp = Hh + (size_t)m * F + q * 4;
#pragma unroll
        for (int nt = 0; nt < 8; ++nt) {
            f16x4 h4 = {(_Float16)acc[nt][0], (_Float16)acc[nt][1],
                        (_Float16)acc[nt][2], (_Float16)acc[nt][3]};
            *(f16x4*)(hp + nt * 16) = h4;
        }
    }
}

__global__ __launch_bounds__(256) void k_bsort(const uint2* __restrict__ temp,
                                               const int* __restrict__ edgeStart,
                                               const int* __restrict__ srcStart,
                                               const int* __restrict__ bucketCnt,
                                               int* __restrict__ rowstart,
                                               int* __restrict__ srcs, int N) {
    __shared__ int cnt[NPB];
    __shared__ int scanE[NPB];
    __shared__ int outS[CAPS];
    __shared__ int wsum[4];
    int b = blockIdx.x, t = threadIdx.x;
    int eBase = edgeStart[b], eCnt = bucketCnt[b];
    int sBase = srcStart[b];
    int nIn = N - b * NPB; nIn = nIn < 0 ? 0 : (nIn > NPB ? NPB : nIn);
    for (int i = t; i < NPB; i += 256) cnt[i] = 1;
    __syncthreads();
    for (int i = t; i < eCnt; i += 256) {
        uint2 e = temp[eBase + i];
        atomicAdd(&cnt[e.y & 0xFF], 1);
    }
    __syncthreads();
    {
        int lane = t & 63, w = t >> 6;
        int c = (t < nIn) ? cnt[t] : 0;
        int x = c;
#pragma unroll
        for (int off = 1; off < 64; off <<= 1) {
            int a = __shfl_up(x, off);
            if (lane >= off) x += a;
        }
        if (lane == 63) wsum[w] = x;
        __syncthreads();
        int o = 0;
        for (int i = 0; i < w; ++i) o += wsum[i];
        if (t < nIn) scanE[t] = o + x - c;
    }
    __syncthreads();
    if (t < nIn) {
        int s0 = scanE[t];
        outS[s0] = b * NPB + t;
        cnt[t] = s0 + 1;
        rowstart[b * NPB + t] = sBase + s0;
    }
    __syncthreads();
    for (int i = t; i < eCnt; i += 256) {
        uint2 e = temp[eBase + i];
        int pos = atomicAdd(&cnt[e.y & 0xFF], 1);
        if (pos < CAPS) outS[pos] = (int)e.x;
    }
    __syncthreads();
    int tot = eCnt + nIn;
    for (int i = t; i < tot; i += 256) srcs[sBase + i] = outS[i];
}

// ---- fused softmax + gather + aggregate + bias (+relu): one wave per dst ----
// lane-group g=lane>>4 owns edge j+g; each of its 16 lanes loads 16 B (8 feats).
// Proven shape: 8-edge main loop + branchless 4-edge tail (VGPR 28).
template <bool RELU, bool OUTH>
__global__ __launch_bounds__(256) void k_aggr(const int* __restrict__ rowstart,
                                              const int* __restrict__ srcs,
                                              const float* __restrict__ As,
                                              const float* __restrict__ Ad,
                                              const _Float16* __restrict__ Hh,
                                              const float* __restrict__ bias,
                                              void* __restrict__ Ov, int N) {
    __shared__ float exs_s[4][256];
    int wid = threadIdx.x >> 6;
    float* exs = exs_s[wid];
    int w = (blockIdx.x << 2) + wid;
    int lane = threadIdx.x & 63;
    if (w >= N) return;
    int d = w;
    int b0 = rowstart[d], b1 = rowstart[d + 1];
    int g = lane >> 4, l16 = lane & 15;
    int h = l16 >> 2;                  // head of this lane's 8 features
    float4 ad4 = ((const float4*)Ad)[d];
    float den = 0.f;
    float acc[8] = {};

    for (int base = b0; base < b1; base += 64) {
        int cnt = min(64, b1 - base);
        int myv = (lane < cnt) ? srcs[base + lane] : 0;
        if (lane < cnt) {              // stage exp for all 4 heads of my edge
            float4 a4 = ((const float4*)As)[myv];
            float4 e;
            e.x = __expf(lrelu(a4.x + ad4.x));
            e.y = __expf(lrelu(a4.y + ad4.y));
            e.z = __expf(lrelu(a4.z + ad4.z));
            e.w = __expf(lrelu(a4.w + ad4.w));
            ((float4*)exs)[lane] = e;
        }
        int j = 0;
        for (; j + 8 <= cnt; j += 8) {     // 8 edges/iter: 2 per lane-group
            int s0 = __shfl(myv, j + g);
            int s1 = __shfl(myv, j + 4 + g);
            float4 q0 = *(const float4*)(Hh + (size_t)s0 * F + 8 * l16);
            float4 q1 = *(const float4*)(Hh + (size_t)s1 * F + 8 * l16);
            float e0 = exs[(j + g) * 4 + h];
            float e1 = exs[(j + 4 + g) * 4 + h];
            den += e0 + e1;
            const __half2* p0 = (const __half2*)&q0;
            const __half2* p1 = (const __half2*)&q1;
#pragma unroll
            for (int u = 0; u < 4; ++u) {
                float2 f0 = __half22float2(p0[u]);
                float2 f1 = __half22float2(p1[u]);
                acc[2 * u]     += e0 * f0.x + e1 * f1.x;
                acc[2 * u + 1] += e0 * f0.y + e1 * f1.y;
            }
        }
        for (; j < cnt; j += 4) {          // branchless tail: 4 edges/iter
            int idx = j + g;
            bool ok = idx < cnt;
            int idxc = ok ? idx : (cnt - 1);
            int s0 = __shfl(myv, idxc);    // all 64 lanes active; src lane active
            float e0 = ok ? exs[idx * 4 + h] : 0.f;
            float4 q0 = *(const float4*)(Hh + (size_t)s0 * F + 8 * l16);
            den += e0;
            const __half2* p0 = (const __half2*)&q0;
#pragma unroll
            for (int u = 0; u < 4; ++u) {
                float2 f0 = __half22float2(p0[u]);
                acc[2 * u]     += e0 * f0.x;
                acc[2 * u + 1] += e0 * f0.y;
            }
        }
    }
#pragma unroll
    for (int i = 0; i < 8; ++i) {
        acc[i] += __shfl_xor(acc[i], 16);
        acc[i] += __shfl_xor(acc[i], 32);
    }
    den += __shfl_xor(den, 16);
    den += __shfl_xor(den, 32);
    float inv = 1.f / (den + 1e-16f);

    if (g == 0) {
        float4 bv0 = ((const float4*)bias)[2 * l16];
        float4 bv1 = ((const float4*)bias)[2 * l16 + 1];
        float o[8];
        o[0] = acc[0] * inv + bv0.x; o[1] = acc[1] * inv + bv0.y;
        o[2] = acc[2] * inv + bv0.z; o[3] = acc[3] * inv + bv0.w;
        o[4] = acc[4] * inv + bv1.x; o[5] = acc[5] * inv + bv1.y;
        o[6] = acc[6] * inv + bv1.z; o[7] = acc[7] * inv + bv1.w;
        if (RELU) {
#pragma unroll
            for (int i = 0; i < 8; ++i) o[i] = fmaxf(o[i], 0.f);
        }
        if (OUTH) {
            f16x8 p;
#pragma unroll
            for (int i = 0; i < 8; ++i) p[i] = (_Float16)o[i];
            *(f16x8*)((_Float16*)Ov + (size_t)d * F + 8 * l16) = p;
        } else {
            float* op = (float*)Ov + (size_t)d * F + 8 * l16;
            *(float4*)op = make_float4(o[0], o[1], o[2], o[3]);
            *(float4*)(op + 4) = make_float4(o[4], o[5], o[6], o[7]);
        }
    }
}

extern "C" void kernel_launch(void* const* d_in, const int* in_sizes, int n_in,
                              void* d_out, int out_size, void* d_ws, size_t ws_size,
                              hipStream_t stream) {
    const float* x   = (const float*)d_in[0];
    const int*   ei  = (const int*)d_in[1];
    const float* W1  = (const float*)d_in[2];
    const float* as1 = (const float*)d_in[3];
    const float* ad1 = (const float*)d_in[4];
    const float* b1  = (const float*)d_in[5];
    const float* W2  = (const float*)d_in[6];
    const float* as2 = (const float*)d_in[7];
    const float* ad2 = (const float*)d_in[8];
    const float* b2  = (const float*)d_in[9];

    int N = in_sizes[0] / F;
    int E = in_sizes[1] / 2;
    const int* src = ei;
    const int* dst = ei + E;

    int gB = (E + BE - 1) / BE;
    int gG = (N + 63) / 64;
    int gW = (N + 3) / 4;

    char* base = (char*)d_ws;
    size_t off = 0;
    _Float16* Hh  = (_Float16*)(base + off); off += (size_t)N * F * 2;
    _Float16* O1h = (_Float16*)(base + off); off += (size_t)N * F * 2;
    float* As  = (float*)(base + off);  off += (size_t)N * HEADS * 4;
    float* Ad  = (float*)(base + off);  off += (size_t)N * HEADS * 4;
    int* rowstart = (int*)(base + off); off += (size_t)(N + 1) * 4;
    off = (off + 15) & ~(size_t)15;
    int* srcs = (int*)(base + off);     off += (size_t)(E + N) * 4;
    off = (off + 15) & ~(size_t)15;
    uint2* temp = (uint2*)(base + off); off += (size_t)E * 8;
    int* bucketCnt   = (int*)(base + off); off += NB * 4;
    int* edgeStart   = (int*)(base + off); off += (NB + 1) * 4;
    int* srcStart    = (int*)(base + off); off += (NB + 1) * 4;
    int* bucketCursor= (int*)(base + off); off += NB * 4;
    off = (off + 15) & ~(size_t)15;
    _Float16* Wt1 = (_Float16*)(base + off); off += 128 * 128 * 2;
    _Float16* Wt2 = (_Float16*)(base + off); off += 128 * 128 * 2;
    off = (off + 15) & ~(size_t)15;
    int* histSlots = (int*)(base + off); off += (size_t)gB * NB * 4;

    dim3 blk(256);

    // -------- weight cvt + per-block hist (merged) --------
    k_wcvt_hist<<<gB + 2, blk, 0, stream>>>(W1, W2, Wt1, Wt2, dst, histSlots, E, gB);
    k_bscan<<<1, NB, 0, stream>>>(histSlots, gB, bucketCnt, edgeStart, srcStart,
                                  bucketCursor, rowstart, N);
    // -------- bucket scatter || layer-1 GEMM (role-split, one dispatch) --------
    k_scat_gemm<<<gB + gG, blk, 0, stream>>>(src, dst, bucketCursor, temp, E, gB,
                                             x, Wt1, as1, ad1, Hh, As, Ad, N);
    k_bsort<<<NB, blk, 0, stream>>>(temp, edgeStart, srcStart, bucketCnt, rowstart, srcs, N);

    // -------- layer 1 aggregate --------
    k_aggr<true, true><<<gW, blk, 0, stream>>>(rowstart, srcs, As, Ad, Hh, b1, O1h, N);

    // -------- layer 2 --------
    k_gemm_mfma<<<gG, blk, 0, stream>>>(O1h, Wt2, as2, ad2, Hh, As, Ad, N);
    k_aggr<false, false><<<gW, blk, 0, stream>>>(rowstart, srcs, As, Ad, Hh, b2, d_out, N);
}